// Round 1
// baseline (214.150 us; speedup 1.0000x reference)
//
#include <hip/hip_runtime.h>
#include <stdint.h>

typedef __bf16 bf16x8 __attribute__((ext_vector_type(8)));
typedef float  f32x4  __attribute__((ext_vector_type(4)));
typedef unsigned short u16;

#define AS1 __attribute__((address_space(1)))
#define AS3 __attribute__((address_space(3)))
#define G2L(gp, lp) __builtin_amdgcn_global_load_lds( \
    (const AS1 unsigned int*)(uintptr_t)(gp), \
    (AS3 unsigned int*)(uintptr_t)(lp), 16, 0, 0)

static __device__ __forceinline__ u16 f32_to_bf16(float f) {
    unsigned u = __float_as_uint(f);
    u += 0x7fffu + ((u >> 16) & 1u);
    return (u16)(u >> 16);
}

static __device__ __forceinline__ f32x4 mfma16(bf16x8 a, bf16x8 b, f32x4 c) {
    return __builtin_amdgcn_mfma_f32_16x16x32_bf16(a, b, c, 0, 0, 0);
}

// ---------------- fp32 -> bf16 convert (vectorized) ----------------
__global__ void cvt_bf16_k(const float* __restrict__ in, u16* __restrict__ out, int n4) {
    int i = blockIdx.x * blockDim.x + threadIdx.x;
    if (i >= n4) return;
    const float4 v = reinterpret_cast<const float4*>(in)[i];
    unsigned p0 = (unsigned)f32_to_bf16(v.x) | ((unsigned)f32_to_bf16(v.y) << 16);
    unsigned p1 = (unsigned)f32_to_bf16(v.z) | ((unsigned)f32_to_bf16(v.w) << 16);
    reinterpret_cast<uint2*>(out)[i] = make_uint2(p0, p1);
}

// ---------------- bf16 GEMM: C[M,N] = A[M,K] @ B[N,K]^T + bias ----------------
// 128x128 tile, BK=32, 4 waves (2x2), each wave 4x4 frags of 16x16x32 MFMA.
template<int OUTF32>
__global__ __launch_bounds__(256) void gemm_bt_k(const u16* __restrict__ A, const u16* __restrict__ B,
                                                 const float* __restrict__ bias, void* __restrict__ Cp,
                                                 int M, int N, int K) {
    __shared__ __align__(16) u16 As[128 * 32];
    __shared__ __align__(16) u16 Bs[128 * 32];
    const int t = threadIdx.x, w = t >> 6, l = t & 63, lr = l & 15, lg = l >> 4;
    const int wr = w >> 1, wc = w & 1;
    const long rowBase = (long)blockIdx.y * 128;
    const long colBase = (long)blockIdx.x * 128;

    const f32x4 z = {0.f, 0.f, 0.f, 0.f};
    f32x4 acc[4][4];
    #pragma unroll
    for (int m = 0; m < 4; ++m)
        #pragma unroll
        for (int n = 0; n < 4; ++n) acc[m][n] = z;

    const int kSteps = K >> 5;
    for (int kt = 0; kt < kSteps; ++kt) {
        const int k0 = kt << 5;
        __syncthreads();
        #pragma unroll
        for (int i = 0; i < 2; ++i) {
            const int c = (i * 4 + w) * 64 + l;       // 512 16B-chunks per tile
            const int row = c >> 2, col = (c & 3) * 8;
            const u16* ga = A + (rowBase + row) * K + k0 + col;
            const u16* gb = B + (colBase + row) * K + k0 + col;
            G2L(ga, As + (i * 4 + w) * 512);
            G2L(gb, Bs + (i * 4 + w) * 512);
        }
        __syncthreads();
        bf16x8 af[4], bfr[4];
        #pragma unroll
        for (int m = 0; m < 4; ++m)
            af[m] = *reinterpret_cast<const bf16x8*>(&As[(wr * 64 + m * 16 + lr) * 32 + lg * 8]);
        #pragma unroll
        for (int n = 0; n < 4; ++n)
            bfr[n] = *reinterpret_cast<const bf16x8*>(&Bs[(wc * 64 + n * 16 + lr) * 32 + lg * 8]);
        #pragma unroll
        for (int m = 0; m < 4; ++m)
            #pragma unroll
            for (int n = 0; n < 4; ++n) acc[m][n] = mfma16(af[m], bfr[n], acc[m][n]);
    }
    #pragma unroll
    for (int n = 0; n < 4; ++n) {
        const long gc = colBase + wc * 64 + n * 16 + lr;
        const float bv = bias[gc];
        #pragma unroll
        for (int m = 0; m < 4; ++m) {
            const long gr = rowBase + wr * 64 + m * 16 + lg * 4;
            #pragma unroll
            for (int r = 0; r < 4; ++r) {
                const float v = acc[m][n][r] + bv;
                if (OUTF32) reinterpret_cast<float*>(Cp)[(gr + r) * N + gc] = v;
                else        reinterpret_cast<u16*>(Cp)[(gr + r) * N + gc] = f32_to_bf16(v);
            }
        }
    }
}

// ---------------- V transpose: qkv V-slice -> vt[bh][64 d][1024 n] ----------------
__global__ __launch_bounds__(256) void transpose_v_k(const u16* __restrict__ qkv, u16* __restrict__ vt) {
    const int bh = blockIdx.y, b = bh / 12, h = bh % 12;
    const int nt = blockIdx.x;
    __shared__ __align__(16) u16 Ts[64][72];
    const int t = threadIdx.x;
    const int rr = t >> 2;
    #pragma unroll
    for (int i = 0; i < 2; ++i) {
        const int ch = (t & 3) + i * 4;
        const u16* src = qkv + (long)(b * 1024 + nt * 64 + rr) * 2304 + 1536 + h * 64 + ch * 8;
        *reinterpret_cast<uint4*>(&Ts[rr][ch * 8]) = *reinterpret_cast<const uint4*>(src);
    }
    __syncthreads();
    #pragma unroll
    for (int i = 0; i < 2; ++i) {
        const int ch = (t & 3) + i * 4;
        u16 vals[8];
        #pragma unroll
        for (int j = 0; j < 8; ++j) vals[j] = Ts[ch * 8 + j][rr];
        u16* dst = vt + (long)(bh * 64 + rr) * 1024 + nt * 64 + ch * 8;
        *reinterpret_cast<uint4*>(dst) = *reinterpret_cast<const uint4*>(vals);
    }
}

// ---------------- flash attention: 4 waves x 16 q-rows, KBLK=64 ----------------
__global__ __launch_bounds__(256) void attn_k(const u16* __restrict__ qkv, const u16* __restrict__ vt,
                                              u16* __restrict__ outp) {
    const int bh = blockIdx.y, b = bh / 12, h = bh % 12;
    const int qt = blockIdx.x;
    const int t = threadIdx.x, w = t >> 6, l = t & 63, lr = l & 15, lg = l >> 4;
    __shared__ __align__(16) u16 Qs[64][72];
    __shared__ __align__(16) u16 Ks[64][72];
    __shared__ __align__(16) u16 Vts[64][72];   // [d][key]
    __shared__ __align__(16) u16 Ps[4][16][72]; // per-wave P: [q][key]

    const int rr = t >> 2;
    #pragma unroll
    for (int i = 0; i < 2; ++i) {
        const int ch = (t & 3) + i * 4;
        const u16* src = qkv + (long)(b * 1024 + qt * 64 + rr) * 2304 + h * 64 + ch * 8;
        *reinterpret_cast<uint4*>(&Qs[rr][ch * 8]) = *reinterpret_cast<const uint4*>(src);
    }
    __syncthreads();
    bf16x8 aq[2];
    aq[0] = *reinterpret_cast<const bf16x8*>(&Qs[w * 16 + lr][lg * 8]);
    aq[1] = *reinterpret_cast<const bf16x8*>(&Qs[w * 16 + lr][32 + lg * 8]);

    const f32x4 z = {0.f, 0.f, 0.f, 0.f};
    f32x4 o[4] = {z, z, z, z};
    float m_i[4] = {-1e30f, -1e30f, -1e30f, -1e30f};
    float l_i[4] = {0.f, 0.f, 0.f, 0.f};
    const float scale = 0.03608439182435161f; // 768^-0.5

    const u16* kb = qkv + 768 + h * 64;
    const u16* vb = vt + (long)bh * 64 * 1024;

    for (int kt = 0; kt < 16; ++kt) {
        __syncthreads();
        #pragma unroll
        for (int i = 0; i < 2; ++i) {
            const int ch = (t & 3) + i * 4;
            *reinterpret_cast<uint4*>(&Ks[rr][ch * 8]) =
                *reinterpret_cast<const uint4*>(kb + (long)(b * 1024 + kt * 64 + rr) * 2304 + ch * 8);
            *reinterpret_cast<uint4*>(&Vts[rr][ch * 8]) =
                *reinterpret_cast<const uint4*>(vb + (long)rr * 1024 + kt * 64 + ch * 8);
        }
        __syncthreads();
        // S = Q @ K^T   (C: col=key=lr-group, row=q=lg*4+r)
        f32x4 s[4] = {z, z, z, z};
        #pragma unroll
        for (int kk = 0; kk < 2; ++kk) {
            #pragma unroll
            for (int kc = 0; kc < 4; ++kc) {
                bf16x8 bk = *reinterpret_cast<const bf16x8*>(&Ks[kc * 16 + lr][kk * 32 + lg * 8]);
                s[kc] = mfma16(aq[kk], bk, s[kc]);
            }
        }
        // online softmax (per q-row = 16-lane group reduce)
        float pvv[4][4];
        #pragma unroll
        for (int r = 0; r < 4; ++r) {
            float mx = fmaxf(fmaxf(s[0][r], s[1][r]), fmaxf(s[2][r], s[3][r])) * scale;
            #pragma unroll
            for (int off = 1; off < 16; off <<= 1) mx = fmaxf(mx, __shfl_xor(mx, off, 64));
            const float mnew = fmaxf(m_i[r], mx);
            const float alpha = __expf(m_i[r] - mnew);
            float rs = 0.f;
            #pragma unroll
            for (int kc = 0; kc < 4; ++kc) {
                const float p = __expf(s[kc][r] * scale - mnew);
                pvv[kc][r] = p; rs += p;
            }
            #pragma unroll
            for (int off = 1; off < 16; off <<= 1) rs += __shfl_xor(rs, off, 64);
            l_i[r] = l_i[r] * alpha + rs;
            m_i[r] = mnew;
            #pragma unroll
            for (int n = 0; n < 4; ++n) o[n][r] *= alpha;
            #pragma unroll
            for (int kc = 0; kc < 4; ++kc)
                Ps[w][lg * 4 + r][kc * 16 + lr] = f32_to_bf16(pvv[kc][r]);
        }
        // O += P @ V  (A=P from Ps, B=V from Vts[d][key])
        #pragma unroll
        for (int kk = 0; kk < 2; ++kk) {
            bf16x8 pa = *reinterpret_cast<const bf16x8*>(&Ps[w][lr][kk * 32 + lg * 8]);
            #pragma unroll
            for (int n = 0; n < 4; ++n) {
                bf16x8 vbf = *reinterpret_cast<const bf16x8*>(&Vts[n * 16 + lr][kk * 32 + lg * 8]);
                o[n] = mfma16(pa, vbf, o[n]);
            }
        }
    }
    const int qrow = qt * 64 + w * 16 + lg * 4;
    #pragma unroll
    for (int n = 0; n < 4; ++n) {
        #pragma unroll
        for (int r = 0; r < 4; ++r) {
            const float v = o[n][r] / l_i[r];
            outp[(long)(b * 1024 + qrow + r) * 768 + h * 64 + n * 16 + lr] = f32_to_bf16(v);
        }
    }
}

extern "C" void kernel_launch(void* const* d_in, const int* in_sizes, int n_in,
                              void* d_out, int out_size, void* d_ws, size_t ws_size,
                              hipStream_t stream) {
    (void)in_sizes; (void)n_in; (void)out_size; (void)ws_size;
    const float* x    = (const float*)d_in[0];
    const float* Wqkv = (const float*)d_in[1];
    const float* bqkv = (const float*)d_in[2];
    const float* Wout = (const float*)d_in[3];
    const float* bout = (const float*)d_in[4];

    u16* xb   = (u16*)d_ws;          // 8192*768
    u16* Wqb  = xb  + 6291456;       // 2304*768
    u16* Wob  = Wqb + 1769472;       // 768*768
    u16* qkv  = Wob + 589824;        // 8192*2304
    u16* vtb  = qkv + 18874368;      // 96*64*1024
    u16* attn = vtb + 6291456;       // 8192*768
    // total ~80.2 MB of workspace

    cvt_bf16_k<<<6144, 256, 0, stream>>>(x, xb, 6291456 / 4);
    cvt_bf16_k<<<1728, 256, 0, stream>>>(Wqkv, Wqb, 1769472 / 4);
    cvt_bf16_k<<<576, 256, 0, stream>>>(Wout, Wob, 589824 / 4);

    gemm_bt_k<0><<<dim3(18, 64), 256, 0, stream>>>(xb, Wqb, bqkv, qkv, 8192, 2304, 768);
    transpose_v_k<<<dim3(16, 96), 256, 0, stream>>>(qkv, vtb);
    attn_k<<<dim3(16, 96), 256, 0, stream>>>(qkv, vtb, attn);
    gemm_bt_k<1><<<dim3(6, 64), 256, 0, stream>>>(attn, Wob, bout, d_out, 8192, 768, 768);
}